// Round 5
// baseline (307.456 us; speedup 1.0000x reference)
//
#include <hip/hip_runtime.h>

typedef __bf16 bf16;
typedef __bf16 bf16x8 __attribute__((ext_vector_type(8)));
typedef float floatx4 __attribute__((ext_vector_type(4)));
typedef float floatx16 __attribute__((ext_vector_type(16)));
typedef unsigned int uint;

#define MFMA16(a, b, c) __builtin_amdgcn_mfma_f32_16x16x32_bf16((a), (b), (c), 0, 0, 0)
#define MFMA32(a, b, c) __builtin_amdgcn_mfma_f32_32x32x16_bf16((a), (b), (c), 0, 0, 0)

// async global->LDS, 16B per lane. LDS side is wave-uniform base (lane0) + lane*16.
__device__ __forceinline__ void gl2lds16(const bf16* g, bf16* l) {
  __builtin_amdgcn_global_load_lds(
      (const __attribute__((address_space(1))) void*)g,
      (__attribute__((address_space(3))) void*)l, 16, 0, 0);
}
// s_waitcnt with vmcnt=N, lgkm=15, exp=7
__device__ __forceinline__ void wait_vm0() { __builtin_amdgcn_s_waitcnt(0x0f70); }

// ---------------------------------------------------------------------------
// fp32 -> bf16 ingest: x | wq | wk | wv | wo, 8 elems/thread.
// ---------------------------------------------------------------------------
__device__ __forceinline__ void cvt8(const float* __restrict__ s,
                                     bf16* __restrict__ d, int i8) {
  const float4 a = ((const float4*)s)[i8 * 2];
  const float4 b = ((const float4*)s)[i8 * 2 + 1];
  bf16x8 o;
  o[0] = (bf16)a.x; o[1] = (bf16)a.y; o[2] = (bf16)a.z; o[3] = (bf16)a.w;
  o[4] = (bf16)b.x; o[5] = (bf16)b.y; o[6] = (bf16)b.z; o[7] = (bf16)b.w;
  *(bf16x8*)(d + i8 * 8) = o;
}

__global__ __launch_bounds__(256) void convert_kernel(
    const float* __restrict__ x, const float* __restrict__ wq,
    const float* __restrict__ wk, const float* __restrict__ wv,
    const float* __restrict__ wo, bf16* __restrict__ xb,
    bf16* __restrict__ wqb, bf16* __restrict__ wkb, bf16* __restrict__ wvb,
    bf16* __restrict__ wob) {
  const int g = blockIdx.x * 256 + threadIdx.x;
  if (g < 524288) cvt8(x, xb, g);
  else if (g < 1048576) cvt8(wq, wqb, g - 524288);
  else if (g < 1179648) cvt8(wk, wkb, g - 1048576);
  else if (g < 1310720) cvt8(wv, wvb, g - 1179648);
  else cvt8(wo, wob, g - 1310720);
}

// ---------------------------------------------------------------------------
// 128x128xK GEMM tile body (round-2 proven structure, BK=32, 16 KB LDS).
// stage 4x gl2lds -> vmcnt(0) -> sync -> ds_read + 16 MFMA -> sync.
// ---------------------------------------------------------------------------
template <typename OutT>
__device__ __forceinline__ void gemm_tile_body32(
    const bf16* __restrict__ A, int lda,
    const bf16* __restrict__ B, int ldb,
    OutT* __restrict__ C, int ldc, int K,
    bf16* As, bf16* Bs) {
  const int t = threadIdx.x;
  const int w = t >> 6, lane = t & 63;
  const int l15 = lane & 15, qd = lane >> 4;
  const int wr = w >> 1, wc = w & 1;

  floatx4 acc[4][4];
#pragma unroll
  for (int i = 0; i < 4; ++i)
#pragma unroll
    for (int j = 0; j < 4; ++j) acc[i][j] = (floatx4){0.f, 0.f, 0.f, 0.f};

  const int mt0 = w, mt1 = w + 4;
  const int kseg = qd * 8;
  const bf16* ga0 = A + (mt0 * 16 + l15) * lda + kseg;
  const bf16* ga1 = A + (mt1 * 16 + l15) * lda + kseg;
  const bf16* gb0 = B + (mt0 * 16 + l15) * ldb + kseg;
  const bf16* gb1 = B + (mt1 * 16 + l15) * ldb + kseg;
  bf16* lA0 = As + mt0 * 512 + lane * 8;
  bf16* lA1 = As + mt1 * 512 + lane * 8;
  bf16* lB0 = Bs + mt0 * 512 + lane * 8;
  bf16* lB1 = Bs + mt1 * 512 + lane * 8;

  for (int k0 = 0; k0 < K; k0 += 32) {
    gl2lds16(ga0 + k0, lA0);
    gl2lds16(ga1 + k0, lA1);
    gl2lds16(gb0 + k0, lB0);
    gl2lds16(gb1 + k0, lB1);
    wait_vm0();
    __syncthreads();

    bf16x8 a[4], b[4];
#pragma unroll
    for (int i = 0; i < 4; ++i)
      a[i] = *(const bf16x8*)(As + (wr * 4 + i) * 512 + lane * 8);
#pragma unroll
    for (int j = 0; j < 4; ++j)
      b[j] = *(const bf16x8*)(Bs + (wc * 4 + j) * 512 + lane * 8);
#pragma unroll
    for (int i = 0; i < 4; ++i)
#pragma unroll
      for (int j = 0; j < 4; ++j) acc[i][j] = MFMA16(a[i], b[j], acc[i][j]);
    __syncthreads();
  }

#pragma unroll
  for (int i = 0; i < 4; ++i)
#pragma unroll
    for (int j = 0; j < 4; ++j) {
      const int row = wr * 64 + i * 16 + qd * 4;
      const int col = wc * 64 + j * 16 + l15;
#pragma unroll
      for (int r = 0; r < 4; ++r)
        C[(row + r) * ldc + col] = (OutT)acc[i][j][r];
    }
}

// ---------------------------------------------------------------------------
// 64x128xK GEMM tile body, BK=64 (round-4 structure) - used by gemm_o.
// ---------------------------------------------------------------------------
template <typename OutT>
__device__ __forceinline__ void gemm_tile_body64(
    const bf16* __restrict__ A, int lda,
    const bf16* __restrict__ B, int ldb,
    OutT* __restrict__ C, int ldc, int K,
    bf16* S) {  // 2 * 12288 bf16
  const int t = threadIdx.x;
  const int w = t >> 6, lane = t & 63;
  const int l15 = lane & 15, qd = lane >> 4;
  const int wr = w >> 1, wc = w & 1;

  floatx4 acc[2][4];
#pragma unroll
  for (int i = 0; i < 2; ++i)
#pragma unroll
    for (int j = 0; j < 4; ++j) acc[i][j] = (floatx4){0.f, 0.f, 0.f, 0.f};

  const bf16* gb[6];
  int lo[6];
#pragma unroll
  for (int i = 0; i < 6; ++i) {
    const int u = w + 4 * i;
    lo[i] = u * 512 + lane * 8;
    if (u < 8) {
      gb[i] = A + ((u >> 1) * 16 + l15) * lda + (u & 1) * 32 + qd * 8;
    } else {
      const int v = u - 8;
      gb[i] = B + ((v >> 1) * 16 + l15) * ldb + (v & 1) * 32 + qd * 8;
    }
  }

#define STG64(kt_, buf_)                                            \
  {                                                                 \
    bf16* d_ = S + (buf_) * 12288;                                  \
    _Pragma("unroll")                                               \
    for (int i_ = 0; i_ < 6; ++i_)                                  \
      gl2lds16(gb[i_] + (kt_) * 64, d_ + lo[i_]);                   \
  }

  const int NT = K >> 6;
  STG64(0, 0);
  wait_vm0();
  __syncthreads();
  int cur = 0;
  for (int kt = 0; kt < NT; ++kt) {
    if (kt + 1 < NT) STG64(kt + 1, cur ^ 1);  // issue next tile early
    const bf16* Ab = S + cur * 12288;
    const bf16* Bb = Ab + 4096;
    bf16x8 a[2][2], b[4][2];
#pragma unroll
    for (int i = 0; i < 2; ++i)
#pragma unroll
      for (int kk = 0; kk < 2; ++kk)
        a[i][kk] =
            *(const bf16x8*)(Ab + ((wr * 2 + i) * 2 + kk) * 512 + lane * 8);
#pragma unroll
    for (int j = 0; j < 4; ++j)
#pragma unroll
      for (int kk = 0; kk < 2; ++kk)
        b[j][kk] =
            *(const bf16x8*)(Bb + ((wc * 4 + j) * 2 + kk) * 512 + lane * 8);
#pragma unroll
    for (int kk = 0; kk < 2; ++kk)
#pragma unroll
      for (int i = 0; i < 2; ++i)
#pragma unroll
        for (int j = 0; j < 4; ++j)
          acc[i][j] = MFMA16(a[i][kk], b[j][kk], acc[i][j]);
    wait_vm0();
    __builtin_amdgcn_sched_barrier(0);
    __builtin_amdgcn_s_barrier();
    __builtin_amdgcn_sched_barrier(0);
    cur ^= 1;
  }
#undef STG64

#pragma unroll
  for (int i = 0; i < 2; ++i)
#pragma unroll
    for (int j = 0; j < 4; ++j) {
      const int row = wr * 32 + i * 16 + qd * 4;
      const int col = wc * 64 + j * 16 + l15;
#pragma unroll
      for (int r = 0; r < 4; ++r)
        C[(row + r) * ldc + col] = (OutT)acc[i][j][r];
    }
}

// ---------------------------------------------------------------------------
// Split-K QKV projection: X(2048x2048) @ [Wq|Wk|Wv]^T, K split in 2 halves.
// grid (24,16,2) = 768 blocks = exactly 3/CU (16 KB LDS). fp32 partials into
// P = d_out viewed as 2 x (2048x3072); every byte of d_out is rewritten later
// (out by gemm_o, kout/vout by rope) so no extra workspace is used.
// ---------------------------------------------------------------------------
__global__ __launch_bounds__(256) void gemm_qkv(
    const bf16* __restrict__ x, const bf16* __restrict__ wq,
    const bf16* __restrict__ wk, const bf16* __restrict__ wv,
    float* __restrict__ P) {
  __shared__ bf16 As[4096], Bs[4096];
  const int m0 = blockIdx.y * 128;
  const int nb = blockIdx.x;
  const int s = blockIdx.z;
  const bf16* B;
  if (nb < 16) B = wq + nb * 128 * 2048;
  else if (nb < 20) B = wk + (nb - 16) * 128 * 2048;
  else B = wv + (nb - 20) * 128 * 2048;
  float* C = P + s * 6291456 + m0 * 3072 + nb * 128;
  gemm_tile_body32<float>(x + m0 * 2048 + s * 1024, 2048, B + s * 1024, 2048,
                          C, 3072, 1024, As, Bs);
}

// ---------------------------------------------------------------------------
// combine_qkv: Q/K/V = bf16(P0 + P1), scatter 3072-wide rows to Qws (2048),
// Kws (512), Vws (512). 3072 blocks x 256 thr, 8 elems/thread.
// ---------------------------------------------------------------------------
__global__ __launch_bounds__(256) void combine_qkv(
    const float* __restrict__ P, bf16* __restrict__ Qws,
    bf16* __restrict__ Kws, bf16* __restrict__ Vws) {
  const int g = blockIdx.x * 256 + threadIdx.x;
  const int base = g * 8;
  const int row = base / 3072;
  const int col = base - row * 3072;
  const float4 a0 = *(const float4*)(P + base);
  const float4 a1 = *(const float4*)(P + base + 4);
  const float4 b0 = *(const float4*)(P + 6291456 + base);
  const float4 b1 = *(const float4*)(P + 6291456 + base + 4);
  bf16x8 o;
  o[0] = (bf16)(a0.x + b0.x); o[1] = (bf16)(a0.y + b0.y);
  o[2] = (bf16)(a0.z + b0.z); o[3] = (bf16)(a0.w + b0.w);
  o[4] = (bf16)(a1.x + b1.x); o[5] = (bf16)(a1.y + b1.y);
  o[6] = (bf16)(a1.z + b1.z); o[7] = (bf16)(a1.w + b1.w);
  bf16* dst;
  if (col < 2048) dst = Qws + row * 2048 + col;
  else if (col < 2560) dst = Kws + row * 512 + (col - 2048);
  else dst = Vws + row * 512 + (col - 2560);
  *(bf16x8*)dst = o;
}

// ---------------------------------------------------------------------------
// Output projection: O(2048x2048) @ Wo^T -> d_out[0:4194304] (fp32).
// grid (16,32) = 512 blocks = exactly 2/CU.
// ---------------------------------------------------------------------------
__global__ __launch_bounds__(256) void gemm_o(
    const bf16* __restrict__ Ows, const bf16* __restrict__ wo,
    float* __restrict__ out) {
  __shared__ bf16 S[24576];
  const int m0 = blockIdx.y * 64, n0 = blockIdx.x * 128;
  gemm_tile_body64<float>(Ows + m0 * 2048, 2048, wo + n0 * 2048, 2048,
                          out + m0 * 2048 + n0, 2048, 2048, S);
}

// ---------------------------------------------------------------------------
// RoPE Q (in place), RoPE K (in place + per-head Kh[kvh][l][64] + fp32 repeat
// to d_out), V repeat to d_out (fp32), V^T [kvh][d][L] (bf16) for flash.
// ---------------------------------------------------------------------------
__global__ __launch_bounds__(256) void rope_repeat_kernel(
    bf16* __restrict__ Qws, bf16* __restrict__ Kws, bf16* __restrict__ Kh,
    const bf16* __restrict__ Vws, bf16* __restrict__ Vt,
    float* __restrict__ kout, float* __restrict__ vout) {
  const int gid = blockIdx.x * 256 + threadIdx.x;
  const float NEG_LOG2_10000_D32 = -0.4152410118609203f;  // -log2(10000)/32
  if (gid < 2097152) {  // Q pairs
    const int l = gid >> 10, pr = gid & 1023, a = pr & 31;
    bf16* p = Qws + l * 2048 + pr * 2;
    const float x0 = (float)p[0], x1 = (float)p[1];
    const float ang = (float)(l + 1) * exp2f(NEG_LOG2_10000_D32 * (float)a);
    float s, c;
    __sincosf(ang, &s, &c);
    p[0] = (bf16)(c * x0 - s * x1);
    p[1] = (bf16)(s * x0 + c * x1);
  } else if (gid < 2097152 + 524288) {  // K pairs
    const int g = gid - 2097152;
    const int l = g >> 8, pr = g & 255, a = pr & 31, kvh = pr >> 5;
    bf16* p = Kws + l * 512 + pr * 2;
    const float x0 = (float)p[0], x1 = (float)p[1];
    const float ang = (float)(l + 1) * exp2f(NEG_LOG2_10000_D32 * (float)a);
    float s, c;
    __sincosf(ang, &s, &c);
    const float y0 = c * x0 - s * x1;
    const float y1 = s * x0 + c * x1;
    p[0] = (bf16)y0;
    p[1] = (bf16)y1;
    bf16* kp = Kh + (kvh * 2048 + l) * 64 + a * 2;
    kp[0] = (bf16)y0;
    kp[1] = (bf16)y1;
#pragma unroll
    for (int rep = 0; rep < 4; ++rep) {
      float* o = kout + (((kvh * 4 + rep) * 2048 + l) * 64 + a * 2);
      o[0] = y0;
      o[1] = y1;
    }
  } else if (gid < 2097152 + 524288 + 131072) {  // V repeat to d_out (fp32)
    const int c = gid - (2097152 + 524288);
    const int l = c >> 6, seg = c & 63, kvh = seg >> 3;
    const bf16x8 v = *(const bf16x8*)(Vws + l * 512 + seg * 8);
    float4 f0, f1;
    f0.x = (float)v[0]; f0.y = (float)v[1]; f0.z = (float)v[2]; f0.w = (float)v[3];
    f1.x = (float)v[4]; f1.y = (float)v[5]; f1.z = (float)v[6]; f1.w = (float)v[7];
#pragma unroll
    for (int rep = 0; rep < 4; ++rep) {
      float* o = vout + (((kvh * 4 + rep) * 2048 + l) * 64 + (seg & 7) * 8);
      *(float4*)o = f0;
      *(float4*)(o + 4) = f1;
    }
  } else {  // V^T build: Vt[kvh][d][l] (bf16)
    const int c = gid - (2097152 + 524288 + 131072);
    const int kvh = c >> 14, r2 = c & 16383, dseg = r2 >> 11, l = r2 & 2047;
    const int d0 = dseg * 8;
    const bf16x8 v = *(const bf16x8*)(Vws + l * 512 + kvh * 64 + d0);
#pragma unroll
    for (int jj = 0; jj < 8; ++jj)
      Vt[kvh * 131072 + (d0 + jj) * 2048 + l] = v[jj];
  }
}

// ---------------------------------------------------------------------------
// Flash attention: split-KV for causal-tail latency (proven structure).
// ---------------------------------------------------------------------------
__global__ __launch_bounds__(256) void flash_kernel(
    const bf16* __restrict__ Qws, const bf16* __restrict__ Kh,
    const bf16* __restrict__ Vt, bf16* __restrict__ Ows,
    float* __restrict__ Opart, float* __restrict__ ML) {
  __shared__ bf16 KVs[2][2][4096];  // [buf][K=0 / V=1][8 slots * 512]
  __shared__ bf16 Osh[128 * 66];    // epilogue transpose, stride 66 (bank-free)

  const int h = blockIdx.y;
  const int bx = blockIdx.x;
  int qt, seg, kts, kte;
  if (bx < 8) {
    qt = bx; seg = -1; kts = 0; kte = 2 * qt + 2;
  } else {
    const int i = bx - 8;
    qt = 8 + (i >> 1);
    seg = i & 1;
    const int half = qt + 1;
    kts = seg * half;
    kte = kts + half;
  }
  const int kh = h >> 2;  // GQA interleaved repeat
  const int q0 = qt * 128;
  const int t = threadIdx.x, w = t >> 6, lane = t & 63;
  const int l31 = lane & 31, hf = lane >> 5;
  const int qw = q0 + w * 32;  // wave's q base; lane's q = qw + l31

  // Q B-fragments: B[k=d][n=q], lane (l31,hf) holds Q[qw+l31][c*16+hf*8+j]
  bf16x8 qf[4];
  {
    const bf16* qrow = Qws + (qw + l31) * 2048 + h * 64 + hf * 8;
#pragma unroll
    for (int c = 0; c < 4; ++c) qf[c] = *(const bf16x8*)(qrow + c * 16);
  }

  floatx16 o[2] = {};  // O^T[m=d' tile n][n=q]: col = q = l31 (lane-owned)
  float mrun = -3e38f, lrun = 0.f;

  // staging: wave w stages K slots {w, w+4} and V slots {w, w+4}
  const int s0 = w, s1 = w + 4;
  const bf16* gK0 = Kh + kh * 131072 + ((s0 >> 2) * 32 + l31) * 64 + (s0 & 3) * 16 + hf * 8;
  const bf16* gK1 = Kh + kh * 131072 + ((s1 >> 2) * 32 + l31) * 64 + (s1 & 3) * 16 + hf * 8;
  const bf16* gV0 = Vt + kh * 131072 + ((s0 >> 2) * 32 + l31) * 2048 + (s0 & 3) * 16 + hf * 8;
  const bf16* gV1 = Vt + kh * 131072 + ((s1 >> 2) * 32 + l31) * 2048 + (s1 & 3) * 16 + hf * 8;

  // prologue: stage kt=kts into buf (kts&1)
  {
    const int nb = kts & 1;
    gl2lds16(gK0 + kts * 4096, &KVs[nb][0][s0 * 512 + lane * 8]);
    gl2lds16(gK1 + kts * 4096, &KVs[nb][0][s1 * 512 + lane * 8]);
    gl2lds16(gV0 + kts * 64, &KVs[nb][1][s0 * 512 + lane * 8]);
    gl2lds16(gV1 + kts * 64, &KVs[nb][1][s1 * 512 + lane * 8]);
  }

  const float C = 0.1803368801f;  // 0.125 * log2(e)
  for (int kt = kts; kt < kte; ++kt) {
    wait_vm0();
    __syncthreads();
    if (kt + 1 < kte) {  // prefetch next tile into other buffer
      const int nb = (kt + 1) & 1;
      const int koff = (kt + 1) * 4096, voff = (kt + 1) * 64;
      gl2lds16(gK0 + koff, &KVs[nb][0][s0 * 512 + lane * 8]);
      gl2lds16(gK1 + koff, &KVs[nb][0][s1 * 512 + lane * 8]);
      gl2lds16(gV0 + voff, &KVs[nb][1][s0 * 512 + lane * 8]);
      gl2lds16(gV1 + voff, &KVs[nb][1][s1 * 512 + lane * 8]);
    }
    const int kt64 = kt * 64;
    if (kt64 > qw + 31) continue;  // fully masked for this wave
    const bf16* Kb = &KVs[kt & 1][0][0];
    const bf16* Vb = &KVs[kt & 1][1][0];

    // S^T = K . Q^T : two 32-key tiles; C/D col = q, row = key local
    floatx16 st[2];
    __builtin_amdgcn_s_setprio(1);
#pragma unroll
    for (int tt = 0; tt < 2; ++tt) {
      floatx16 z = {};
#pragma unroll
      for (int c = 0; c < 4; ++c) {
        const bf16x8 kf = *(const bf16x8*)(Kb + (tt * 4 + c) * 512 + lane * 8);
        z = MFMA32(kf, qf[c], z);
      }
      st[tt] = z;
    }
    __builtin_amdgcn_s_setprio(0);
    // causal mask (diagonal region only); key = kt64+tt*32+(r&3)+8*(r>>2)+4*hf
    if (kt64 + 64 > qw) {
      const int myq = qw + l31;
#pragma unroll
      for (int tt = 0; tt < 2; ++tt)
#pragma unroll
        for (int r = 0; r < 16; ++r) {
          const int key = kt64 + tt * 32 + (r & 3) + 8 * (r >> 2) + 4 * hf;
          if (key > myq) st[tt][r] = -1e30f;
        }
    }
    // online softmax: lane-scalar m/l; 4-way tree max then hf-pair reduce
    float ma = -3e38f, mb = -3e38f, mc = -3e38f, md = -3e38f;
#pragma unroll
    for (int tt = 0; tt < 2; ++tt)
#pragma unroll
      for (int r = 0; r < 16; r += 4) {
        ma = fmaxf(ma, st[tt][r + 0]);
        mb = fmaxf(mb, st[tt][r + 1]);
        mc = fmaxf(mc, st[tt][r + 2]);
        md = fmaxf(md, st[tt][r + 3]);
      }
    float mx = fmaxf(fmaxf(ma, mb), fmaxf(mc, md));
    mx = fmaxf(mx, __shfl_xor(mx, 32));
    // defer-max (T13): skip rescale while P stays bounded by 2^8
    const bool defer = __all((mx - mrun) * C <= 8.f);
    if (!defer) {
      const float mn = fmaxf(mrun, mx);
      const float al = __builtin_amdgcn_exp2f((mrun - mn) * C);
      lrun *= al;
#pragma unroll
      for (int n = 0; n < 2; ++n)
#pragma unroll
        for (int r = 0; r < 16; ++r) o[n][r] *= al;
      mrun = mn;
    }
    float ra = 0.f, rb = 0.f, rc = 0.f, rd = 0.f;
#pragma unroll
    for (int tt = 0; tt < 2; ++tt)
#pragma unroll
      for (int r = 0; r < 16; r += 4) {
        const float p0 = __builtin_amdgcn_exp2f((st[tt][r + 0] - mrun) * C);
        const float p1 = __builtin_amdgcn_exp2f((st[tt][r + 1] - mrun) * C);
        const float p2 = __builtin_amdgcn_exp2f((st[tt][r + 2] - mrun) * C);
        const float p3 = __builtin_amdgcn_exp2f((st[tt][r + 3] - mrun) * C);
        st[tt][r + 0] = p0; ra += p0;
        st[tt][r + 1] = p1; rb += p1;
        st[tt][r + 2] = p2; rc += p2;
        st[tt][r + 3] = p3; rd += p3;
      }
    float rs = (ra + rb) + (rc + rd);
    rs += __shfl_xor(rs, 32);
    lrun += rs;

    // P^T B-frags from S^T C/D via half-exchange (owner hf = j>>2):
    // pk[tt][g][p] packs keys m = 8g + 4*hf + 2p + {0,1} (consecutive dword)
    uint pk[2][4][2];
#pragma unroll
    for (int tt = 0; tt < 2; ++tt)
#pragma unroll
      for (int g = 0; g < 4; ++g)
#pragma unroll
        for (int p = 0; p < 2; ++p) {
          union { bf16 h2[2]; uint u; } cv;
          cv.h2[0] = (bf16)st[tt][4 * g + 2 * p];
          cv.h2[1] = (bf16)st[tt][4 * g + 2 * p + 1];
          pk[tt][g][p] = cv.u;
        }
    uint own_[2][2][2], rv[2][2][2];
#pragma unroll
    for (int tt = 0; tt < 2; ++tt)
#pragma unroll
      for (int gam = 0; gam < 2; ++gam)
#pragma unroll
        for (int p = 0; p < 2; ++p) {
          own_[tt][gam][p] = hf ? pk[tt][2 * gam + 1][p] : pk[tt][2 * gam][p];
          const uint snd = hf ? pk[tt][2 * gam][p] : pk[tt][2 * gam + 1][p];
          rv[tt][gam][p] = (uint)__shfl_xor((int)snd, 32);
        }
    // chunk c = tt*2+gam covers keys [c*16, c*16+16); dwords 0,1 from hf=0 owner
    __builtin_amdgcn_s_setprio(1);
#pragma unroll
    for (int c = 0; c < 4; ++c) {
      const int tt = c >> 1, gam = c & 1;
      union { uint u[4]; bf16x8 v; } pf;
      pf.u[0] = hf ? rv[tt][gam][0] : own_[tt][gam][0];
      pf.u[1] = hf ? rv[tt][gam][1] : own_[tt][gam][1];
      pf.u[2] = hf ? own_[tt][gam][0] : rv[tt][gam][0];
      pf.u[3] = hf ? own_[tt][gam][1] : rv[tt][gam][1];
      // O^T = V^T . P^T : A = V chunk (m = d'), B = P^T chunk (n = q)
#pragma unroll
      for (int n = 0; n < 2; ++n)
        o[n] = MFMA32(*(const bf16x8*)(Vb + (n * 4 + c) * 512 + lane * 8),
                      pf.v, o[n]);
    }
    __builtin_amdgcn_s_setprio(0);
  }

  if (seg < 0) {
    // full block: normalize, O^T C/D -> LDS transpose -> coalesced store.
    // lane holds O[q = qw+l31][d' = n*32 + (r&3)+8*(r>>2)+4*hf]
    const float inv = 1.f / lrun;
#pragma unroll
    for (int n = 0; n < 2; ++n)
#pragma unroll
      for (int r = 0; r < 16; ++r) {
        const int dl = n * 32 + (r & 3) + 8 * (r >> 2) + 4 * hf;
        Osh[(w * 32 + l31) * 66 + dl] = (bf16)(o[n][r] * inv);
      }
    __syncthreads();
#pragma unroll
    for (int i = 0; i < 4; ++i) {
      const int row = (t >> 3) + i * 32;
      const int col = (t & 7) * 8;
      const bf16x8 vv = *(const bf16x8*)&Osh[row * 66 + col];
      *(bf16x8*)&Ows[(q0 + row) * 2048 + h * 64 + col] = vv;
    }
  } else {
    // partial block: unnormalized fp32 O^T [d'][row] + per-row (m, l)
    const int idx = (h * 8 + (qt - 8)) * 2 + seg;
    float* Op = Opart + idx * 8192;
#pragma unroll
    for (int n = 0; n < 2; ++n)
#pragma unroll
      for (int r = 0; r < 16; ++r) {
        const int dl = n * 32 + (r & 3) + 8 * (r >> 2) + 4 * hf;
        Op[dl * 128 + w * 32 + l31] = o[n][r];
      }
    if (hf == 0) {
      ML[idx * 256 + w * 32 + l31] = mrun;
      ML[idx * 256 + 128 + w * 32 + l31] = lrun;
    }
  }
}

// ---------------------------------------------------------------------------
// Combine two KV-segment partials per (h, qt>=8): O = (O0*w0 + O1*w1)/denom.
// ---------------------------------------------------------------------------
__global__ __launch_bounds__(256) void combine_kernel(
    const float* __restrict__ Opart, const float* __restrict__ ML,
    bf16* __restrict__ Ows) {
  __shared__ bf16 Osh[128 * 66];
  const int b = blockIdx.x;
  const int h = b >> 3, qt = (b & 7) + 8;
  const int q0 = qt * 128;
  const int t = threadIdx.x;
  const int row = t & 127, dh = t >> 7;
  const int i0 = (h * 8 + (qt - 8)) * 2;
  const float C = 0.1803368801f;  // 0.125 * log2(e)
  const float m0 = ML[i0 * 256 + row], l0 = ML[i0 * 256 + 128 + row];
  const float m1 = ML[(i0 + 1) * 256 + row], l1 = ML[(i0 + 1) * 256 + 128 + row];
  const float m = fmaxf(m0, m1);
  const float w0 = __builtin_amdgcn_exp2f((m0 - m) * C);
  const float w1 = __builtin_amdgcn_exp2f((m1 - m) * C);
  const float inv = 1.f / (l0 * w0 + l1 * w1);
  const float* P0 = Opart + i0 * 8192;
  const float* P1 = Opart + (i0 + 1) * 8192;
#pragma unroll
  for (int j = 0; j < 32; ++j) {
    const int d = dh * 32 + j;
    const float v = (P0[d * 128 + row] * w0 + P1[d * 128 + row] * w1) * inv;
    Osh[row * 66 + d] = (bf16)v;
  }
  __syncthreads();
#pragma unroll
  for (int i = 0; i < 4; ++i) {
    const int r2 = (t >> 3) + i * 32;
    const int col = (t & 7) * 8;
    const bf16x8 vv = *(const bf16x8*)&Osh[r2 * 66 + col];
    *(bf16x8*)&Ows[(q0 + r2) * 2048 + h * 64 + col] = vv;
  }
}

// ---------------------------------------------------------------------------
extern "C" void kernel_launch(void* const* d_in, const int* in_sizes, int n_in,
                              void* d_out, int out_size, void* d_ws,
                              size_t ws_size, hipStream_t stream) {
  const float* x = (const float*)d_in[0];
  // d_in[1] = mask: causality recomputed in-kernel, unused.
  const float* wq = (const float*)d_in[2];
  const float* wk = (const float*)d_in[3];
  const float* wv = (const float*)d_in[4];
  const float* wo = (const float*)d_in[5];

  float* out = (float*)d_out;            // (2048, 2048) fp32
  float* kout = out + 4194304;           // (32, 2048, 64) fp32
  float* vout = out + 8388608;           // (32, 2048, 64) fp32

  bf16* ws = (bf16*)d_ws;
  bf16* xb = ws;                         // 2048 x 2048
  bf16* wqb = xb + 4194304;              // 2048 x 2048
  bf16* wkb = wqb + 4194304;             // 512 x 2048
  bf16* wvb = wkb + 1048576;             // 512 x 2048
  bf16* wob = wvb + 1048576;             // 2048 x 2048
  bf16* Qws = wob + 4194304;             // 2048 x 2048
  bf16* Kws = Qws + 4194304;             // 2048 x 512
  bf16* Vws = Kws + 1048576;             // 2048 x 512
  bf16* Vt = Vws + 1048576;              // 8 x 64 x 2048 (V^T per kv head)
  bf16* Ows = Vt + 1048576;              // 2048 x 2048 (attention out)
  bf16* Kh = Ows + 4194304;              // 8 x 2048 x 64 (roped K per kv head)
  // Scratch aliases (no new workspace):
  //  - QKV split-K fp32 partials: ALL of d_out (2 x 6291456 floats =
  //    12582912 = exact d_out size); dead before rope overwrites kout/vout
  //    and gemm_o overwrites out.
  //  - flash split-KV partials Opart: the `out` region (rewritten by gemm_o).
  //  - flash ML: Kws region (dead after rope).
  float* Pqkv = out;
  float* Opart = out;
  float* MLf = (float*)Kws;              // 512 x 256 fp32 (m,l partials)

  convert_kernel<<<dim3(7168), dim3(256), 0, stream>>>(x, wq, wk, wv, wo, xb,
                                                       wqb, wkb, wvb, wob);
  gemm_qkv<<<dim3(24, 16, 2), dim3(256), 0, stream>>>(xb, wqb, wkb, wvb, Pqkv);
  combine_qkv<<<dim3(3072), dim3(256), 0, stream>>>(Pqkv, Qws, Kws, Vws);
  rope_repeat_kernel<<<dim3(11264), dim3(256), 0, stream>>>(Qws, Kws, Kh, Vws,
                                                            Vt, kout, vout);
  flash_kernel<<<dim3(24, 32), dim3(256), 0, stream>>>(Qws, Kh, Vt, Ows, Opart,
                                                       MLf);
  combine_kernel<<<dim3(256), dim3(256), 0, stream>>>(Opart, MLf, Ows);
  gemm_o<<<dim3(16, 32), dim3(256), 0, stream>>>(Ows, wob, out);
}

// Round 6
// 289.031 us; speedup vs baseline: 1.0637x; 1.0637x over previous
//
#include <hip/hip_runtime.h>

typedef __bf16 bf16;
typedef __bf16 bf16x8 __attribute__((ext_vector_type(8)));
typedef float floatx4 __attribute__((ext_vector_type(4)));
typedef float floatx16 __attribute__((ext_vector_type(16)));
typedef unsigned int uint;

#define MFMA16(a, b, c) __builtin_amdgcn_mfma_f32_16x16x32_bf16((a), (b), (c), 0, 0, 0)
#define MFMA32(a, b, c) __builtin_amdgcn_mfma_f32_32x32x16_bf16((a), (b), (c), 0, 0, 0)

// async global->LDS, 16B per lane. LDS side is wave-uniform base (lane0) + lane*16.
__device__ __forceinline__ void gl2lds16(const bf16* g, bf16* l) {
  __builtin_amdgcn_global_load_lds(
      (const __attribute__((address_space(1))) void*)g,
      (__attribute__((address_space(3))) void*)l, 16, 0, 0);
}
// s_waitcnt with vmcnt=N, lgkm=15, exp=7
__device__ __forceinline__ void wait_vm0() { __builtin_amdgcn_s_waitcnt(0x0f70); }

// ---------------------------------------------------------------------------
// fp32 -> bf16 ingest: x | wq | wk | wv | wo, 8 elems/thread.
// ---------------------------------------------------------------------------
__device__ __forceinline__ void cvt8(const float* __restrict__ s,
                                     bf16* __restrict__ d, int i8) {
  const float4 a = ((const float4*)s)[i8 * 2];
  const float4 b = ((const float4*)s)[i8 * 2 + 1];
  bf16x8 o;
  o[0] = (bf16)a.x; o[1] = (bf16)a.y; o[2] = (bf16)a.z; o[3] = (bf16)a.w;
  o[4] = (bf16)b.x; o[5] = (bf16)b.y; o[6] = (bf16)b.z; o[7] = (bf16)b.w;
  *(bf16x8*)(d + i8 * 8) = o;
}

__global__ __launch_bounds__(256) void convert_kernel(
    const float* __restrict__ x, const float* __restrict__ wq,
    const float* __restrict__ wk, const float* __restrict__ wv,
    const float* __restrict__ wo, bf16* __restrict__ xb,
    bf16* __restrict__ wqb, bf16* __restrict__ wkb, bf16* __restrict__ wvb,
    bf16* __restrict__ wob) {
  const int g = blockIdx.x * 256 + threadIdx.x;
  if (g < 524288) cvt8(x, xb, g);
  else if (g < 1048576) cvt8(wq, wqb, g - 524288);
  else if (g < 1179648) cvt8(wk, wkb, g - 1048576);
  else if (g < 1310720) cvt8(wv, wvb, g - 1179648);
  else cvt8(wo, wob, g - 1310720);
}

// ---------------------------------------------------------------------------
// 128x128xK GEMM tile body (round-2 proven structure, BK=32, 16 KB LDS).
// stage 4x gl2lds -> vmcnt(0) -> sync -> ds_read + 16 MFMA -> sync.
// ---------------------------------------------------------------------------
template <typename OutT>
__device__ __forceinline__ void gemm_tile_body32(
    const bf16* __restrict__ A, int lda,
    const bf16* __restrict__ B, int ldb,
    OutT* __restrict__ C, int ldc, int K,
    bf16* As, bf16* Bs) {
  const int t = threadIdx.x;
  const int w = t >> 6, lane = t & 63;
  const int l15 = lane & 15, qd = lane >> 4;
  const int wr = w >> 1, wc = w & 1;

  floatx4 acc[4][4];
#pragma unroll
  for (int i = 0; i < 4; ++i)
#pragma unroll
    for (int j = 0; j < 4; ++j) acc[i][j] = (floatx4){0.f, 0.f, 0.f, 0.f};

  const int mt0 = w, mt1 = w + 4;
  const int kseg = qd * 8;
  const bf16* ga0 = A + (mt0 * 16 + l15) * lda + kseg;
  const bf16* ga1 = A + (mt1 * 16 + l15) * lda + kseg;
  const bf16* gb0 = B + (mt0 * 16 + l15) * ldb + kseg;
  const bf16* gb1 = B + (mt1 * 16 + l15) * ldb + kseg;
  bf16* lA0 = As + mt0 * 512 + lane * 8;
  bf16* lA1 = As + mt1 * 512 + lane * 8;
  bf16* lB0 = Bs + mt0 * 512 + lane * 8;
  bf16* lB1 = Bs + mt1 * 512 + lane * 8;

  for (int k0 = 0; k0 < K; k0 += 32) {
    gl2lds16(ga0 + k0, lA0);
    gl2lds16(ga1 + k0, lA1);
    gl2lds16(gb0 + k0, lB0);
    gl2lds16(gb1 + k0, lB1);
    wait_vm0();
    __syncthreads();

    bf16x8 a[4], b[4];
#pragma unroll
    for (int i = 0; i < 4; ++i)
      a[i] = *(const bf16x8*)(As + (wr * 4 + i) * 512 + lane * 8);
#pragma unroll
    for (int j = 0; j < 4; ++j)
      b[j] = *(const bf16x8*)(Bs + (wc * 4 + j) * 512 + lane * 8);
#pragma unroll
    for (int i = 0; i < 4; ++i)
#pragma unroll
      for (int j = 0; j < 4; ++j) acc[i][j] = MFMA16(a[i], b[j], acc[i][j]);
    __syncthreads();
  }

#pragma unroll
  for (int i = 0; i < 4; ++i)
#pragma unroll
    for (int j = 0; j < 4; ++j) {
      const int row = wr * 64 + i * 16 + qd * 4;
      const int col = wc * 64 + j * 16 + l15;
#pragma unroll
      for (int r = 0; r < 4; ++r)
        C[(row + r) * ldc + col] = (OutT)acc[i][j][r];
    }
}

// ---------------------------------------------------------------------------
// 64x128xK GEMM tile body, BK=64 (round-4 structure) - used by gemm_o.
// ---------------------------------------------------------------------------
template <typename OutT>
__device__ __forceinline__ void gemm_tile_body64(
    const bf16* __restrict__ A, int lda,
    const bf16* __restrict__ B, int ldb,
    OutT* __restrict__ C, int ldc, int K,
    bf16* S) {  // 2 * 12288 bf16
  const int t = threadIdx.x;
  const int w = t >> 6, lane = t & 63;
  const int l15 = lane & 15, qd = lane >> 4;
  const int wr = w >> 1, wc = w & 1;

  floatx4 acc[2][4];
#pragma unroll
  for (int i = 0; i < 2; ++i)
#pragma unroll
    for (int j = 0; j < 4; ++j) acc[i][j] = (floatx4){0.f, 0.f, 0.f, 0.f};

  const bf16* gb[6];
  int lo[6];
#pragma unroll
  for (int i = 0; i < 6; ++i) {
    const int u = w + 4 * i;
    lo[i] = u * 512 + lane * 8;
    if (u < 8) {
      gb[i] = A + ((u >> 1) * 16 + l15) * lda + (u & 1) * 32 + qd * 8;
    } else {
      const int v = u - 8;
      gb[i] = B + ((v >> 1) * 16 + l15) * ldb + (v & 1) * 32 + qd * 8;
    }
  }

#define STG64(kt_, buf_)                                            \
  {                                                                 \
    bf16* d_ = S + (buf_) * 12288;                                  \
    _Pragma("unroll")                                               \
    for (int i_ = 0; i_ < 6; ++i_)                                  \
      gl2lds16(gb[i_] + (kt_) * 64, d_ + lo[i_]);                   \
  }

  const int NT = K >> 6;
  STG64(0, 0);
  wait_vm0();
  __syncthreads();
  int cur = 0;
  for (int kt = 0; kt < NT; ++kt) {
    if (kt + 1 < NT) STG64(kt + 1, cur ^ 1);  // issue next tile early
    const bf16* Ab = S + cur * 12288;
    const bf16* Bb = Ab + 4096;
    bf16x8 a[2][2], b[4][2];
#pragma unroll
    for (int i = 0; i < 2; ++i)
#pragma unroll
      for (int kk = 0; kk < 2; ++kk)
        a[i][kk] =
            *(const bf16x8*)(Ab + ((wr * 2 + i) * 2 + kk) * 512 + lane * 8);
#pragma unroll
    for (int j = 0; j < 4; ++j)
#pragma unroll
      for (int kk = 0; kk < 2; ++kk)
        b[j][kk] =
            *(const bf16x8*)(Bb + ((wc * 4 + j) * 2 + kk) * 512 + lane * 8);
#pragma unroll
    for (int kk = 0; kk < 2; ++kk)
#pragma unroll
      for (int i = 0; i < 2; ++i)
#pragma unroll
        for (int j = 0; j < 4; ++j)
          acc[i][j] = MFMA16(a[i][kk], b[j][kk], acc[i][j]);
    wait_vm0();
    __builtin_amdgcn_sched_barrier(0);
    __builtin_amdgcn_s_barrier();
    __builtin_amdgcn_sched_barrier(0);
    cur ^= 1;
  }
#undef STG64

#pragma unroll
  for (int i = 0; i < 2; ++i)
#pragma unroll
    for (int j = 0; j < 4; ++j) {
      const int row = wr * 32 + i * 16 + qd * 4;
      const int col = wc * 64 + j * 16 + l15;
#pragma unroll
      for (int r = 0; r < 4; ++r)
        C[(row + r) * ldc + col] = (OutT)acc[i][j][r];
    }
}

// ---------------------------------------------------------------------------
// Fused QKV projection: X(2048x2048) @ [Wq|Wk|Wv]^T, 128x128 tiles, bf16 out.
// T1 XCD-chunked swizzle: flat bid -> swz=(bid%8)*48+bid/8 (bijective, 384%8
// ==0). XCD j owns logical tiles [48j,48j+48) = 2 m-rows x all 24 nb -> A/B
// panel re-reads become same-XCD L2 hits instead of cross-XCD L3 traffic.
// ---------------------------------------------------------------------------
__global__ __launch_bounds__(256) void gemm_qkv(
    const bf16* __restrict__ x, const bf16* __restrict__ wq,
    const bf16* __restrict__ wk, const bf16* __restrict__ wv,
    bf16* __restrict__ Qws, bf16* __restrict__ Kws, bf16* __restrict__ Vws) {
  __shared__ bf16 As[4096], Bs[4096];
  const int bid = blockIdx.y * 24 + blockIdx.x;
  const int swz = (bid & 7) * 48 + (bid >> 3);
  const int nb = swz % 24;
  const int m0 = (swz / 24) * 128;
  const bf16* B;
  bf16* C;
  int ldc;
  if (nb < 16) {
    B = wq + nb * 128 * 2048;
    C = Qws + m0 * 2048 + nb * 128;
    ldc = 2048;
  } else if (nb < 20) {
    B = wk + (nb - 16) * 128 * 2048;
    C = Kws + m0 * 512 + (nb - 16) * 128;
    ldc = 512;
  } else {
    B = wv + (nb - 20) * 128 * 2048;
    C = Vws + m0 * 512 + (nb - 20) * 128;
    ldc = 512;
  }
  gemm_tile_body32<bf16>(x + m0 * 2048, 2048, B, 2048, C, ldc, 2048, As, Bs);
}

// ---------------------------------------------------------------------------
// Output projection: O(2048x2048) @ Wo^T -> d_out[0:4194304] (fp32).
// grid 512 blocks = 2/CU; T1 chunked swizzle (chunk 64 = 4 m x 16 n per XCD).
// ---------------------------------------------------------------------------
__global__ __launch_bounds__(256) void gemm_o(
    const bf16* __restrict__ Ows, const bf16* __restrict__ wo,
    float* __restrict__ out) {
  __shared__ bf16 S[24576];
  const int bid = blockIdx.y * 16 + blockIdx.x;
  const int swz = (bid & 7) * 64 + (bid >> 3);
  const int n0 = (swz & 15) * 128;
  const int m0 = (swz >> 4) * 64;
  gemm_tile_body64<float>(Ows + m0 * 2048, 2048, wo + n0 * 2048, 2048,
                          out + m0 * 2048 + n0, 2048, 2048, S);
}

// ---------------------------------------------------------------------------
// RoPE Q (in place), RoPE K (in place + per-head Kh[kvh][l][64] + fp32 repeat
// to d_out), V repeat to d_out (fp32), V^T [kvh][d][L] (bf16) for flash.
// ---------------------------------------------------------------------------
__global__ __launch_bounds__(256) void rope_repeat_kernel(
    bf16* __restrict__ Qws, bf16* __restrict__ Kws, bf16* __restrict__ Kh,
    const bf16* __restrict__ Vws, bf16* __restrict__ Vt,
    float* __restrict__ kout, float* __restrict__ vout) {
  const int gid = blockIdx.x * 256 + threadIdx.x;
  const float NEG_LOG2_10000_D32 = -0.4152410118609203f;  // -log2(10000)/32
  if (gid < 2097152) {  // Q pairs
    const int l = gid >> 10, pr = gid & 1023, a = pr & 31;
    bf16* p = Qws + l * 2048 + pr * 2;
    const float x0 = (float)p[0], x1 = (float)p[1];
    const float ang = (float)(l + 1) * exp2f(NEG_LOG2_10000_D32 * (float)a);
    float s, c;
    __sincosf(ang, &s, &c);
    p[0] = (bf16)(c * x0 - s * x1);
    p[1] = (bf16)(s * x0 + c * x1);
  } else if (gid < 2097152 + 524288) {  // K pairs
    const int g = gid - 2097152;
    const int l = g >> 8, pr = g & 255, a = pr & 31, kvh = pr >> 5;
    bf16* p = Kws + l * 512 + pr * 2;
    const float x0 = (float)p[0], x1 = (float)p[1];
    const float ang = (float)(l + 1) * exp2f(NEG_LOG2_10000_D32 * (float)a);
    float s, c;
    __sincosf(ang, &s, &c);
    const float y0 = c * x0 - s * x1;
    const float y1 = s * x0 + c * x1;
    p[0] = (bf16)y0;
    p[1] = (bf16)y1;
    bf16* kp = Kh + (kvh * 2048 + l) * 64 + a * 2;
    kp[0] = (bf16)y0;
    kp[1] = (bf16)y1;
#pragma unroll
    for (int rep = 0; rep < 4; ++rep) {
      float* o = kout + (((kvh * 4 + rep) * 2048 + l) * 64 + a * 2);
      o[0] = y0;
      o[1] = y1;
    }
  } else if (gid < 2097152 + 524288 + 131072) {  // V repeat to d_out (fp32)
    const int c = gid - (2097152 + 524288);
    const int l = c >> 6, seg = c & 63, kvh = seg >> 3;
    const bf16x8 v = *(const bf16x8*)(Vws + l * 512 + seg * 8);
    float4 f0, f1;
    f0.x = (float)v[0]; f0.y = (float)v[1]; f0.z = (float)v[2]; f0.w = (float)v[3];
    f1.x = (float)v[4]; f1.y = (float)v[5]; f1.z = (float)v[6]; f1.w = (float)v[7];
#pragma unroll
    for (int rep = 0; rep < 4; ++rep) {
      float* o = vout + (((kvh * 4 + rep) * 2048 + l) * 64 + (seg & 7) * 8);
      *(float4*)o = f0;
      *(float4*)(o + 4) = f1;
    }
  } else {  // V^T build: Vt[kvh][d][l] (bf16)
    const int c = gid - (2097152 + 524288 + 131072);
    const int kvh = c >> 14, r2 = c & 16383, dseg = r2 >> 11, l = r2 & 2047;
    const int d0 = dseg * 8;
    const bf16x8 v = *(const bf16x8*)(Vws + l * 512 + kvh * 64 + d0);
#pragma unroll
    for (int jj = 0; jj < 8; ++jj)
      Vt[kvh * 131072 + (d0 + jj) * 2048 + l] = v[jj];
  }
}

// ---------------------------------------------------------------------------
// Flash attention: split-KV for causal-tail latency (proven structure).
// ---------------------------------------------------------------------------
__global__ __launch_bounds__(256) void flash_kernel(
    const bf16* __restrict__ Qws, const bf16* __restrict__ Kh,
    const bf16* __restrict__ Vt, bf16* __restrict__ Ows,
    float* __restrict__ Opart, float* __restrict__ ML) {
  __shared__ bf16 KVs[2][2][4096];  // [buf][K=0 / V=1][8 slots * 512]
  __shared__ bf16 Osh[128 * 66];    // epilogue transpose, stride 66 (bank-free)

  const int h = blockIdx.y;
  const int bx = blockIdx.x;
  int qt, seg, kts, kte;
  if (bx < 8) {
    qt = bx; seg = -1; kts = 0; kte = 2 * qt + 2;
  } else {
    const int i = bx - 8;
    qt = 8 + (i >> 1);
    seg = i & 1;
    const int half = qt + 1;
    kts = seg * half;
    kte = kts + half;
  }
  const int kh = h >> 2;  // GQA interleaved repeat
  const int q0 = qt * 128;
  const int t = threadIdx.x, w = t >> 6, lane = t & 63;
  const int l31 = lane & 31, hf = lane >> 5;
  const int qw = q0 + w * 32;  // wave's q base; lane's q = qw + l31

  // Q B-fragments: B[k=d][n=q], lane (l31,hf) holds Q[qw+l31][c*16+hf*8+j]
  bf16x8 qf[4];
  {
    const bf16* qrow = Qws + (qw + l31) * 2048 + h * 64 + hf * 8;
#pragma unroll
    for (int c = 0; c < 4; ++c) qf[c] = *(const bf16x8*)(qrow + c * 16);
  }

  floatx16 o[2] = {};  // O^T[m=d' tile n][n=q]: col = q = l31 (lane-owned)
  float mrun = -3e38f, lrun = 0.f;

  // staging: wave w stages K slots {w, w+4} and V slots {w, w+4}
  const int s0 = w, s1 = w + 4;
  const bf16* gK0 = Kh + kh * 131072 + ((s0 >> 2) * 32 + l31) * 64 + (s0 & 3) * 16 + hf * 8;
  const bf16* gK1 = Kh + kh * 131072 + ((s1 >> 2) * 32 + l31) * 64 + (s1 & 3) * 16 + hf * 8;
  const bf16* gV0 = Vt + kh * 131072 + ((s0 >> 2) * 32 + l31) * 2048 + (s0 & 3) * 16 + hf * 8;
  const bf16* gV1 = Vt + kh * 131072 + ((s1 >> 2) * 32 + l31) * 2048 + (s1 & 3) * 16 + hf * 8;

  // prologue: stage kt=kts into buf (kts&1)
  {
    const int nb = kts & 1;
    gl2lds16(gK0 + kts * 4096, &KVs[nb][0][s0 * 512 + lane * 8]);
    gl2lds16(gK1 + kts * 4096, &KVs[nb][0][s1 * 512 + lane * 8]);
    gl2lds16(gV0 + kts * 64, &KVs[nb][1][s0 * 512 + lane * 8]);
    gl2lds16(gV1 + kts * 64, &KVs[nb][1][s1 * 512 + lane * 8]);
  }

  const float C = 0.1803368801f;  // 0.125 * log2(e)
  for (int kt = kts; kt < kte; ++kt) {
    wait_vm0();
    __syncthreads();
    if (kt + 1 < kte) {  // prefetch next tile into other buffer
      const int nb = (kt + 1) & 1;
      const int koff = (kt + 1) * 4096, voff = (kt + 1) * 64;
      gl2lds16(gK0 + koff, &KVs[nb][0][s0 * 512 + lane * 8]);
      gl2lds16(gK1 + koff, &KVs[nb][0][s1 * 512 + lane * 8]);
      gl2lds16(gV0 + voff, &KVs[nb][1][s0 * 512 + lane * 8]);
      gl2lds16(gV1 + voff, &KVs[nb][1][s1 * 512 + lane * 8]);
    }
    const int kt64 = kt * 64;
    if (kt64 > qw + 31) continue;  // fully masked for this wave
    const bf16* Kb = &KVs[kt & 1][0][0];
    const bf16* Vb = &KVs[kt & 1][1][0];

    // S^T = K . Q^T : two 32-key tiles; C/D col = q, row = key local
    floatx16 st[2];
    __builtin_amdgcn_s_setprio(1);
#pragma unroll
    for (int tt = 0; tt < 2; ++tt) {
      floatx16 z = {};
#pragma unroll
      for (int c = 0; c < 4; ++c) {
        const bf16x8 kf = *(const bf16x8*)(Kb + (tt * 4 + c) * 512 + lane * 8);
        z = MFMA32(kf, qf[c], z);
      }
      st[tt] = z;
    }
    __builtin_amdgcn_s_setprio(0);
    // causal mask (diagonal region only); key = kt64+tt*32+(r&3)+8*(r>>2)+4*hf
    if (kt64 + 64 > qw) {
      const int myq = qw + l31;
#pragma unroll
      for (int tt = 0; tt < 2; ++tt)
#pragma unroll
        for (int r = 0; r < 16; ++r) {
          const int key = kt64 + tt * 32 + (r & 3) + 8 * (r >> 2) + 4 * hf;
          if (key > myq) st[tt][r] = -1e30f;
        }
    }
    // online softmax: lane-scalar m/l; 4-way tree max then hf-pair reduce
    float ma = -3e38f, mb = -3e38f, mc = -3e38f, md = -3e38f;
#pragma unroll
    for (int tt = 0; tt < 2; ++tt)
#pragma unroll
      for (int r = 0; r < 16; r += 4) {
        ma = fmaxf(ma, st[tt][r + 0]);
        mb = fmaxf(mb, st[tt][r + 1]);
        mc = fmaxf(mc, st[tt][r + 2]);
        md = fmaxf(md, st[tt][r + 3]);
      }
    float mx = fmaxf(fmaxf(ma, mb), fmaxf(mc, md));
    mx = fmaxf(mx, __shfl_xor(mx, 32));
    // defer-max (T13): skip rescale while P stays bounded by 2^8
    const bool defer = __all((mx - mrun) * C <= 8.f);
    if (!defer) {
      const float mn = fmaxf(mrun, mx);
      const float al = __builtin_amdgcn_exp2f((mrun - mn) * C);
      lrun *= al;
#pragma unroll
      for (int n = 0; n < 2; ++n)
#pragma unroll
        for (int r = 0; r < 16; ++r) o[n][r] *= al;
      mrun = mn;
    }
    float ra = 0.f, rb = 0.f, rc = 0.f, rd = 0.f;
#pragma unroll
    for (int tt = 0; tt < 2; ++tt)
#pragma unroll
      for (int r = 0; r < 16; r += 4) {
        const float p0 = __builtin_amdgcn_exp2f((st[tt][r + 0] - mrun) * C);
        const float p1 = __builtin_amdgcn_exp2f((st[tt][r + 1] - mrun) * C);
        const float p2 = __builtin_amdgcn_exp2f((st[tt][r + 2] - mrun) * C);
        const float p3 = __builtin_amdgcn_exp2f((st[tt][r + 3] - mrun) * C);
        st[tt][r + 0] = p0; ra += p0;
        st[tt][r + 1] = p1; rb += p1;
        st[tt][r + 2] = p2; rc += p2;
        st[tt][r + 3] = p3; rd += p3;
      }
    float rs = (ra + rb) + (rc + rd);
    rs += __shfl_xor(rs, 32);
    lrun += rs;

    // P^T B-frags from S^T C/D via half-exchange (owner hf = j>>2):
    // pk[tt][g][p] packs keys m = 8g + 4*hf + 2p + {0,1} (consecutive dword)
    uint pk[2][4][2];
#pragma unroll
    for (int tt = 0; tt < 2; ++tt)
#pragma unroll
      for (int g = 0; g < 4; ++g)
#pragma unroll
        for (int p = 0; p < 2; ++p) {
          union { bf16 h2[2]; uint u; } cv;
          cv.h2[0] = (bf16)st[tt][4 * g + 2 * p];
          cv.h2[1] = (bf16)st[tt][4 * g + 2 * p + 1];
          pk[tt][g][p] = cv.u;
        }
    uint own_[2][2][2], rv[2][2][2];
#pragma unroll
    for (int tt = 0; tt < 2; ++tt)
#pragma unroll
      for (int gam = 0; gam < 2; ++gam)
#pragma unroll
        for (int p = 0; p < 2; ++p) {
          own_[tt][gam][p] = hf ? pk[tt][2 * gam + 1][p] : pk[tt][2 * gam][p];
          const uint snd = hf ? pk[tt][2 * gam][p] : pk[tt][2 * gam + 1][p];
          rv[tt][gam][p] = (uint)__shfl_xor((int)snd, 32);
        }
    // chunk c = tt*2+gam covers keys [c*16, c*16+16); dwords 0,1 from hf=0 owner
    __builtin_amdgcn_s_setprio(1);
#pragma unroll
    for (int c = 0; c < 4; ++c) {
      const int tt = c >> 1, gam = c & 1;
      union { uint u[4]; bf16x8 v; } pf;
      pf.u[0] = hf ? rv[tt][gam][0] : own_[tt][gam][0];
      pf.u[1] = hf ? rv[tt][gam][1] : own_[tt][gam][1];
      pf.u[2] = hf ? own_[tt][gam][0] : rv[tt][gam][0];
      pf.u[3] = hf ? own_[tt][gam][1] : rv[tt][gam][1];
      // O^T = V^T . P^T : A = V chunk (m = d'), B = P^T chunk (n = q)
#pragma unroll
      for (int n = 0; n < 2; ++n)
        o[n] = MFMA32(*(const bf16x8*)(Vb + (n * 4 + c) * 512 + lane * 8),
                      pf.v, o[n]);
    }
    __builtin_amdgcn_s_setprio(0);
  }

  if (seg < 0) {
    // full block: normalize, O^T C/D -> LDS transpose -> coalesced store.
    // lane holds O[q = qw+l31][d' = n*32 + (r&3)+8*(r>>2)+4*hf]
    const float inv = 1.f / lrun;
#pragma unroll
    for (int n = 0; n < 2; ++n)
#pragma unroll
      for (int r = 0; r < 16; ++r) {
        const int dl = n * 32 + (r & 3) + 8 * (r >> 2) + 4 * hf;
        Osh[(w * 32 + l31) * 66 + dl] = (bf16)(o[n][r] * inv);
      }
    __syncthreads();
#pragma unroll
    for (int i = 0; i < 4; ++i) {
      const int row = (t >> 3) + i * 32;
      const int col = (t & 7) * 8;
      const bf16x8 vv = *(const bf16x8*)&Osh[row * 66 + col];
      *(bf16x8*)&Ows[(q0 + row) * 2048 + h * 64 + col] = vv;
    }
  } else {
    // partial block: unnormalized fp32 O^T [d'][row] + per-row (m, l)
    const int idx = (h * 8 + (qt - 8)) * 2 + seg;
    float* Op = Opart + idx * 8192;
#pragma unroll
    for (int n = 0; n < 2; ++n)
#pragma unroll
      for (int r = 0; r < 16; ++r) {
        const int dl = n * 32 + (r & 3) + 8 * (r >> 2) + 4 * hf;
        Op[dl * 128 + w * 32 + l31] = o[n][r];
      }
    if (hf == 0) {
      ML[idx * 256 + w * 32 + l31] = mrun;
      ML[idx * 256 + 128 + w * 32 + l31] = lrun;
    }
  }
}

// ---------------------------------------------------------------------------
// Combine two KV-segment partials per (h, qt>=8): O = (O0*w0 + O1*w1)/denom.
// ---------------------------------------------------------------------------
__global__ __launch_bounds__(256) void combine_kernel(
    const float* __restrict__ Opart, const float* __restrict__ ML,
    bf16* __restrict__ Ows) {
  __shared__ bf16 Osh[128 * 66];
  const int b = blockIdx.x;
  const int h = b >> 3, qt = (b & 7) + 8;
  const int q0 = qt * 128;
  const int t = threadIdx.x;
  const int row = t & 127, dh = t >> 7;
  const int i0 = (h * 8 + (qt - 8)) * 2;
  const float C = 0.1803368801f;  // 0.125 * log2(e)
  const float m0 = ML[i0 * 256 + row], l0 = ML[i0 * 256 + 128 + row];
  const float m1 = ML[(i0 + 1) * 256 + row], l1 = ML[(i0 + 1) * 256 + 128 + row];
  const float m = fmaxf(m0, m1);
  const float w0 = __builtin_amdgcn_exp2f((m0 - m) * C);
  const float w1 = __builtin_amdgcn_exp2f((m1 - m) * C);
  const float inv = 1.f / (l0 * w0 + l1 * w1);
  const float* P0 = Opart + i0 * 8192;
  const float* P1 = Opart + (i0 + 1) * 8192;
#pragma unroll
  for (int j = 0; j < 32; ++j) {
    const int d = dh * 32 + j;
    const float v = (P0[d * 128 + row] * w0 + P1[d * 128 + row] * w1) * inv;
    Osh[row * 66 + d] = (bf16)v;
  }
  __syncthreads();
#pragma unroll
  for (int i = 0; i < 4; ++i) {
    const int r2 = (t >> 3) + i * 32;
    const int col = (t & 7) * 8;
    const bf16x8 vv = *(const bf16x8*)&Osh[r2 * 66 + col];
    *(bf16x8*)&Ows[(q0 + r2) * 2048 + h * 64 + col] = vv;
  }
}

// ---------------------------------------------------------------------------
extern "C" void kernel_launch(void* const* d_in, const int* in_sizes, int n_in,
                              void* d_out, int out_size, void* d_ws,
                              size_t ws_size, hipStream_t stream) {
  const float* x = (const float*)d_in[0];
  // d_in[1] = mask: causality recomputed in-kernel, unused.
  const float* wq = (const float*)d_in[2];
  const float* wk = (const float*)d_in[3];
  const float* wv = (const float*)d_in[4];
  const float* wo = (const float*)d_in[5];

  float* out = (float*)d_out;            // (2048, 2048) fp32
  float* kout = out + 4194304;           // (32, 2048, 64) fp32
  float* vout = out + 8388608;           // (32, 2048, 64) fp32

  bf16* ws = (bf16*)d_ws;
  bf16* xb = ws;                         // 2048 x 2048
  bf16* wqb = xb + 4194304;              // 2048 x 2048
  bf16* wkb = wqb + 4194304;             // 512 x 2048
  bf16* wvb = wkb + 1048576;             // 512 x 2048
  bf16* wob = wvb + 1048576;             // 2048 x 2048
  bf16* Qws = wob + 4194304;             // 2048 x 2048
  bf16* Kws = Qws + 4194304;             // 2048 x 512
  bf16* Vws = Kws + 1048576;             // 2048 x 512
  bf16* Vt = Vws + 1048576;              // 8 x 64 x 2048 (V^T per kv head)
  bf16* Ows = Vt + 1048576;              // 2048 x 2048 (attention out)
  bf16* Kh = Ows + 4194304;              // 8 x 2048 x 64 (roped K per kv head)
  // Scratch aliases (no new workspace): flash split-KV partials Opart = the
  // `out` region (rewritten by gemm_o); flash ML = Kws region (dead after
  // rope).
  float* Opart = out;
  float* MLf = (float*)Kws;              // 512 x 256 fp32 (m,l partials)

  convert_kernel<<<dim3(7168), dim3(256), 0, stream>>>(x, wq, wk, wv, wo, xb,
                                                       wqb, wkb, wvb, wob);
  gemm_qkv<<<dim3(24, 16), dim3(256), 0, stream>>>(xb, wqb, wkb, wvb, Qws, Kws,
                                                   Vws);
  rope_repeat_kernel<<<dim3(11264), dim3(256), 0, stream>>>(Qws, Kws, Kh, Vws,
                                                            Vt, kout, vout);
  flash_kernel<<<dim3(24, 32), dim3(256), 0, stream>>>(Qws, Kh, Vt, Ows, Opart,
                                                       MLf);
  combine_kernel<<<dim3(256), dim3(256), 0, stream>>>(Opart, MLf, Ows);
  gemm_o<<<dim3(16, 32), dim3(256), 0, stream>>>(Ows, wob, out);
}

// Round 7
// 288.697 us; speedup vs baseline: 1.0650x; 1.0012x over previous
//
#include <hip/hip_runtime.h>

typedef __bf16 bf16;
typedef __bf16 bf16x8 __attribute__((ext_vector_type(8)));
typedef float floatx4 __attribute__((ext_vector_type(4)));
typedef float floatx16 __attribute__((ext_vector_type(16)));
typedef unsigned int uint;

#define MFMA16(a, b, c) __builtin_amdgcn_mfma_f32_16x16x32_bf16((a), (b), (c), 0, 0, 0)
#define MFMA32(a, b, c) __builtin_amdgcn_mfma_f32_32x32x16_bf16((a), (b), (c), 0, 0, 0)

// async global->LDS, 16B per lane. LDS side is wave-uniform base (lane0) + lane*16.
__device__ __forceinline__ void gl2lds16(const bf16* g, bf16* l) {
  __builtin_amdgcn_global_load_lds(
      (const __attribute__((address_space(1))) void*)g,
      (__attribute__((address_space(3))) void*)l, 16, 0, 0);
}
// s_waitcnt with vmcnt=N, lgkm=15, exp=7
__device__ __forceinline__ void wait_vm0() { __builtin_amdgcn_s_waitcnt(0x0f70); }

// ---------------------------------------------------------------------------
// fp32 -> bf16 ingest: x | wq | wk | wv | wo, 8 elems/thread.
// ---------------------------------------------------------------------------
__device__ __forceinline__ void cvt8(const float* __restrict__ s,
                                     bf16* __restrict__ d, int i8) {
  const float4 a = ((const float4*)s)[i8 * 2];
  const float4 b = ((const float4*)s)[i8 * 2 + 1];
  bf16x8 o;
  o[0] = (bf16)a.x; o[1] = (bf16)a.y; o[2] = (bf16)a.z; o[3] = (bf16)a.w;
  o[4] = (bf16)b.x; o[5] = (bf16)b.y; o[6] = (bf16)b.z; o[7] = (bf16)b.w;
  *(bf16x8*)(d + i8 * 8) = o;
}

__global__ __launch_bounds__(256) void convert_kernel(
    const float* __restrict__ x, const float* __restrict__ wq,
    const float* __restrict__ wk, const float* __restrict__ wv,
    const float* __restrict__ wo, bf16* __restrict__ xb,
    bf16* __restrict__ wqb, bf16* __restrict__ wkb, bf16* __restrict__ wvb,
    bf16* __restrict__ wob) {
  const int g = blockIdx.x * 256 + threadIdx.x;
  if (g < 524288) cvt8(x, xb, g);
  else if (g < 1048576) cvt8(wq, wqb, g - 524288);
  else if (g < 1179648) cvt8(wk, wkb, g - 1048576);
  else if (g < 1310720) cvt8(wv, wvb, g - 1179648);
  else cvt8(wo, wob, g - 1310720);
}

// ---------------------------------------------------------------------------
// 64x128xK GEMM tile body, BK=64 (round-4 structure) - used by gemm_o.
// ---------------------------------------------------------------------------
template <typename OutT>
__device__ __forceinline__ void gemm_tile_body64(
    const bf16* __restrict__ A, int lda,
    const bf16* __restrict__ B, int ldb,
    OutT* __restrict__ C, int ldc, int K,
    bf16* S) {  // 2 * 12288 bf16
  const int t = threadIdx.x;
  const int w = t >> 6, lane = t & 63;
  const int l15 = lane & 15, qd = lane >> 4;
  const int wr = w >> 1, wc = w & 1;

  floatx4 acc[2][4];
#pragma unroll
  for (int i = 0; i < 2; ++i)
#pragma unroll
    for (int j = 0; j < 4; ++j) acc[i][j] = (floatx4){0.f, 0.f, 0.f, 0.f};

  const bf16* gb[6];
  int lo[6];
#pragma unroll
  for (int i = 0; i < 6; ++i) {
    const int u = w + 4 * i;
    lo[i] = u * 512 + lane * 8;
    if (u < 8) {
      gb[i] = A + ((u >> 1) * 16 + l15) * lda + (u & 1) * 32 + qd * 8;
    } else {
      const int v = u - 8;
      gb[i] = B + ((v >> 1) * 16 + l15) * ldb + (v & 1) * 32 + qd * 8;
    }
  }

#define STG64(kt_, buf_)                                            \
  {                                                                 \
    bf16* d_ = S + (buf_) * 12288;                                  \
    _Pragma("unroll")                                               \
    for (int i_ = 0; i_ < 6; ++i_)                                  \
      gl2lds16(gb[i_] + (kt_) * 64, d_ + lo[i_]);                   \
  }

  const int NT = K >> 6;
  STG64(0, 0);
  wait_vm0();
  __syncthreads();
  int cur = 0;
  for (int kt = 0; kt < NT; ++kt) {
    if (kt + 1 < NT) STG64(kt + 1, cur ^ 1);  // issue next tile early
    const bf16* Ab = S + cur * 12288;
    const bf16* Bb = Ab + 4096;
    bf16x8 a[2][2], b[4][2];
#pragma unroll
    for (int i = 0; i < 2; ++i)
#pragma unroll
      for (int kk = 0; kk < 2; ++kk)
        a[i][kk] =
            *(const bf16x8*)(Ab + ((wr * 2 + i) * 2 + kk) * 512 + lane * 8);
#pragma unroll
    for (int j = 0; j < 4; ++j)
#pragma unroll
      for (int kk = 0; kk < 2; ++kk)
        b[j][kk] =
            *(const bf16x8*)(Bb + ((wc * 4 + j) * 2 + kk) * 512 + lane * 8);
#pragma unroll
    for (int kk = 0; kk < 2; ++kk)
#pragma unroll
      for (int i = 0; i < 2; ++i)
#pragma unroll
        for (int j = 0; j < 4; ++j)
          acc[i][j] = MFMA16(a[i][kk], b[j][kk], acc[i][j]);
    wait_vm0();
    __builtin_amdgcn_sched_barrier(0);
    __builtin_amdgcn_s_barrier();
    __builtin_amdgcn_sched_barrier(0);
    cur ^= 1;
  }
#undef STG64

#pragma unroll
  for (int i = 0; i < 2; ++i)
#pragma unroll
    for (int j = 0; j < 4; ++j) {
      const int row = wr * 32 + i * 16 + qd * 4;
      const int col = wc * 64 + j * 16 + l15;
#pragma unroll
      for (int r = 0; r < 4; ++r)
        C[(row + r) * ldc + col] = (OutT)acc[i][j][r];
    }
}

// ---------------------------------------------------------------------------
// Fused QKV projection + RoPE + GQA repeat + V^T build (rope_repeat fused
// into the epilogue; rope pairs are adjacent columns = adjacent lanes ->
// one shfl_xor(1) per element).
//   nb<16 (Q): write roped Q to Qws.
//   nb 16-19 (K): write roped K to Kh[kvh][l][64] + fp32 x4 repeat to kout.
//   nb 20-23 (V): write fp32 x4 repeat to vout + V^T (bf16) to Vt.
// Kws/Vws intermediates are eliminated entirely.
// T1 XCD-chunked swizzle kept from round 6.
// ---------------------------------------------------------------------------
__global__ __launch_bounds__(256) void gemm_qkv(
    const bf16* __restrict__ x, const bf16* __restrict__ wq,
    const bf16* __restrict__ wk, const bf16* __restrict__ wv,
    bf16* __restrict__ Qws, bf16* __restrict__ Kh, bf16* __restrict__ Vt,
    float* __restrict__ kout, float* __restrict__ vout) {
  __shared__ bf16 As[4096], Bs[4096];
  const int bid = blockIdx.y * 24 + blockIdx.x;
  const int swz = (bid & 7) * 48 + (bid >> 3);
  const int nb = swz % 24;
  const int m0 = (swz / 24) * 128;
  const bf16* B;
  if (nb < 16) B = wq + nb * 128 * 2048;
  else if (nb < 20) B = wk + (nb - 16) * 128 * 2048;
  else B = wv + (nb - 20) * 128 * 2048;

  const int t = threadIdx.x;
  const int w = t >> 6, lane = t & 63;
  const int l15 = lane & 15, qd = lane >> 4;
  const int wr = w >> 1, wc = w & 1;

  floatx4 acc[4][4];
#pragma unroll
  for (int i = 0; i < 4; ++i)
#pragma unroll
    for (int j = 0; j < 4; ++j) acc[i][j] = (floatx4){0.f, 0.f, 0.f, 0.f};

  const bf16* A = x + m0 * 2048;
  const int mt0 = w, mt1 = w + 4;
  const int kseg = qd * 8;
  const bf16* ga0 = A + (mt0 * 16 + l15) * 2048 + kseg;
  const bf16* ga1 = A + (mt1 * 16 + l15) * 2048 + kseg;
  const bf16* gb0 = B + (mt0 * 16 + l15) * 2048 + kseg;
  const bf16* gb1 = B + (mt1 * 16 + l15) * 2048 + kseg;
  bf16* lA0 = As + mt0 * 512 + lane * 8;
  bf16* lA1 = As + mt1 * 512 + lane * 8;
  bf16* lB0 = Bs + mt0 * 512 + lane * 8;
  bf16* lB1 = Bs + mt1 * 512 + lane * 8;

  for (int k0 = 0; k0 < 2048; k0 += 32) {
    gl2lds16(ga0 + k0, lA0);
    gl2lds16(ga1 + k0, lA1);
    gl2lds16(gb0 + k0, lB0);
    gl2lds16(gb1 + k0, lB1);
    wait_vm0();
    __syncthreads();

    bf16x8 a[4], b[4];
#pragma unroll
    for (int i = 0; i < 4; ++i)
      a[i] = *(const bf16x8*)(As + (wr * 4 + i) * 512 + lane * 8);
#pragma unroll
    for (int j = 0; j < 4; ++j)
      b[j] = *(const bf16x8*)(Bs + (wc * 4 + j) * 512 + lane * 8);
#pragma unroll
    for (int i = 0; i < 4; ++i)
#pragma unroll
      for (int j = 0; j < 4; ++j) acc[i][j] = MFMA16(a[i], b[j], acc[i][j]);
    __syncthreads();
  }

  // ---- fused epilogue ----
  const float NEG_LOG2_10000_D32 = -0.4152410118609203f;  // -log2(10000)/32
  const int odd = l15 & 1;  // column parity; partner value lives in lane^1
#pragma unroll
  for (int i = 0; i < 4; ++i)
#pragma unroll
    for (int j = 0; j < 4; ++j) {
      const int row = wr * 64 + i * 16 + qd * 4;       // local row
      const int col = wc * 64 + j * 16 + l15;          // local col in tile
#pragma unroll
      for (int r = 0; r < 4; ++r) {
        const float own = acc[i][j][r];
        const int rg = m0 + row + r;                   // global seq position
        if (nb < 16) {                                 // ---- Q: rope, store
          const float part = __shfl_xor(own, 1);
          const int gcol = nb * 128 + col;
          const int a = (gcol & 63) >> 1;
          const float ang =
              (float)(rg + 1) * exp2f(NEG_LOG2_10000_D32 * (float)a);
          float s, c;
          __sincosf(ang, &s, &c);
          const float val = odd ? (s * part + c * own) : (c * own - s * part);
          Qws[rg * 2048 + gcol] = (bf16)val;
        } else if (nb < 20) {                          // ---- K: rope, Kh+kout
          const float part = __shfl_xor(own, 1);
          const int g512 = (nb - 16) * 128 + col;
          const int kvh = g512 >> 6, d = g512 & 63;
          const int a = d >> 1;
          const float ang =
              (float)(rg + 1) * exp2f(NEG_LOG2_10000_D32 * (float)a);
          float s, c;
          __sincosf(ang, &s, &c);
          const float val = odd ? (s * part + c * own) : (c * own - s * part);
          Kh[(kvh * 2048 + rg) * 64 + d] = (bf16)val;
          float* o = kout + (kvh * 4 * 2048 + rg) * 64 + d;
#pragma unroll
          for (int rep = 0; rep < 4; ++rep) o[rep * 131072] = val;
        } else {                                       // ---- V: vout + Vt
          const int g512 = (nb - 20) * 128 + col;
          const int kvh = g512 >> 6, d = g512 & 63;
          float* o = vout + (kvh * 4 * 2048 + rg) * 64 + d;
#pragma unroll
          for (int rep = 0; rep < 4; ++rep) o[rep * 131072] = own;
          Vt[kvh * 131072 + d * 2048 + rg] = (bf16)own;
        }
      }
    }
}

// ---------------------------------------------------------------------------
// Output projection: O(2048x2048) @ Wo^T -> d_out[0:4194304] (fp32).
// grid 512 blocks = 2/CU; T1 chunked swizzle (chunk 64 = 4 m x 16 n per XCD).
// ---------------------------------------------------------------------------
__global__ __launch_bounds__(256) void gemm_o(
    const bf16* __restrict__ Ows, const bf16* __restrict__ wo,
    float* __restrict__ out) {
  __shared__ bf16 S[24576];
  const int bid = blockIdx.y * 16 + blockIdx.x;
  const int swz = (bid & 7) * 64 + (bid >> 3);
  const int n0 = (swz & 15) * 128;
  const int m0 = (swz >> 4) * 64;
  gemm_tile_body64<float>(Ows + m0 * 2048, 2048, wo + n0 * 2048, 2048,
                          out + m0 * 2048 + n0, 2048, 2048, S);
}

// ---------------------------------------------------------------------------
// Flash attention: split-KV for causal-tail latency (proven structure).
// ---------------------------------------------------------------------------
__global__ __launch_bounds__(256) void flash_kernel(
    const bf16* __restrict__ Qws, const bf16* __restrict__ Kh,
    const bf16* __restrict__ Vt, bf16* __restrict__ Ows,
    float* __restrict__ Opart, float* __restrict__ ML) {
  __shared__ bf16 KVs[2][2][4096];  // [buf][K=0 / V=1][8 slots * 512]
  __shared__ bf16 Osh[128 * 66];    // epilogue transpose, stride 66 (bank-free)

  const int h = blockIdx.y;
  const int bx = blockIdx.x;
  int qt, seg, kts, kte;
  if (bx < 8) {
    qt = bx; seg = -1; kts = 0; kte = 2 * qt + 2;
  } else {
    const int i = bx - 8;
    qt = 8 + (i >> 1);
    seg = i & 1;
    const int half = qt + 1;
    kts = seg * half;
    kte = kts + half;
  }
  const int kh = h >> 2;  // GQA interleaved repeat
  const int q0 = qt * 128;
  const int t = threadIdx.x, w = t >> 6, lane = t & 63;
  const int l31 = lane & 31, hf = lane >> 5;
  const int qw = q0 + w * 32;  // wave's q base; lane's q = qw + l31

  // Q B-fragments: B[k=d][n=q], lane (l31,hf) holds Q[qw+l31][c*16+hf*8+j]
  bf16x8 qf[4];
  {
    const bf16* qrow = Qws + (qw + l31) * 2048 + h * 64 + hf * 8;
#pragma unroll
    for (int c = 0; c < 4; ++c) qf[c] = *(const bf16x8*)(qrow + c * 16);
  }

  floatx16 o[2] = {};  // O^T[m=d' tile n][n=q]: col = q = l31 (lane-owned)
  float mrun = -3e38f, lrun = 0.f;

  // staging: wave w stages K slots {w, w+4} and V slots {w, w+4}
  const int s0 = w, s1 = w + 4;
  const bf16* gK0 = Kh + kh * 131072 + ((s0 >> 2) * 32 + l31) * 64 + (s0 & 3) * 16 + hf * 8;
  const bf16* gK1 = Kh + kh * 131072 + ((s1 >> 2) * 32 + l31) * 64 + (s1 & 3) * 16 + hf * 8;
  const bf16* gV0 = Vt + kh * 131072 + ((s0 >> 2) * 32 + l31) * 2048 + (s0 & 3) * 16 + hf * 8;
  const bf16* gV1 = Vt + kh * 131072 + ((s1 >> 2) * 32 + l31) * 2048 + (s1 & 3) * 16 + hf * 8;

  // prologue: stage kt=kts into buf (kts&1)
  {
    const int nb = kts & 1;
    gl2lds16(gK0 + kts * 4096, &KVs[nb][0][s0 * 512 + lane * 8]);
    gl2lds16(gK1 + kts * 4096, &KVs[nb][0][s1 * 512 + lane * 8]);
    gl2lds16(gV0 + kts * 64, &KVs[nb][1][s0 * 512 + lane * 8]);
    gl2lds16(gV1 + kts * 64, &KVs[nb][1][s1 * 512 + lane * 8]);
  }

  const float C = 0.1803368801f;  // 0.125 * log2(e)
  for (int kt = kts; kt < kte; ++kt) {
    wait_vm0();
    __syncthreads();
    if (kt + 1 < kte) {  // prefetch next tile into other buffer
      const int nb = (kt + 1) & 1;
      const int koff = (kt + 1) * 4096, voff = (kt + 1) * 64;
      gl2lds16(gK0 + koff, &KVs[nb][0][s0 * 512 + lane * 8]);
      gl2lds16(gK1 + koff, &KVs[nb][0][s1 * 512 + lane * 8]);
      gl2lds16(gV0 + voff, &KVs[nb][1][s0 * 512 + lane * 8]);
      gl2lds16(gV1 + voff, &KVs[nb][1][s1 * 512 + lane * 8]);
    }
    const int kt64 = kt * 64;
    if (kt64 > qw + 31) continue;  // fully masked for this wave
    const bf16* Kb = &KVs[kt & 1][0][0];
    const bf16* Vb = &KVs[kt & 1][1][0];

    // S^T = K . Q^T : two 32-key tiles; C/D col = q, row = key local
    floatx16 st[2];
    __builtin_amdgcn_s_setprio(1);
#pragma unroll
    for (int tt = 0; tt < 2; ++tt) {
      floatx16 z = {};
#pragma unroll
      for (int c = 0; c < 4; ++c) {
        const bf16x8 kf = *(const bf16x8*)(Kb + (tt * 4 + c) * 512 + lane * 8);
        z = MFMA32(kf, qf[c], z);
      }
      st[tt] = z;
    }
    __builtin_amdgcn_s_setprio(0);
    // causal mask (diagonal region only); key = kt64+tt*32+(r&3)+8*(r>>2)+4*hf
    if (kt64 + 64 > qw) {
      const int myq = qw + l31;
#pragma unroll
      for (int tt = 0; tt < 2; ++tt)
#pragma unroll
        for (int r = 0; r < 16; ++r) {
          const int key = kt64 + tt * 32 + (r & 3) + 8 * (r >> 2) + 4 * hf;
          if (key > myq) st[tt][r] = -1e30f;
        }
    }
    // online softmax: lane-scalar m/l; 4-way tree max then hf-pair reduce
    float ma = -3e38f, mb = -3e38f, mc = -3e38f, md = -3e38f;
#pragma unroll
    for (int tt = 0; tt < 2; ++tt)
#pragma unroll
      for (int r = 0; r < 16; r += 4) {
        ma = fmaxf(ma, st[tt][r + 0]);
        mb = fmaxf(mb, st[tt][r + 1]);
        mc = fmaxf(mc, st[tt][r + 2]);
        md = fmaxf(md, st[tt][r + 3]);
      }
    float mx = fmaxf(fmaxf(ma, mb), fmaxf(mc, md));
    mx = fmaxf(mx, __shfl_xor(mx, 32));
    // defer-max (T13): skip rescale while P stays bounded by 2^8
    const bool defer = __all((mx - mrun) * C <= 8.f);
    if (!defer) {
      const float mn = fmaxf(mrun, mx);
      const float al = __builtin_amdgcn_exp2f((mrun - mn) * C);
      lrun *= al;
#pragma unroll
      for (int n = 0; n < 2; ++n)
#pragma unroll
        for (int r = 0; r < 16; ++r) o[n][r] *= al;
      mrun = mn;
    }
    float ra = 0.f, rb = 0.f, rc = 0.f, rd = 0.f;
#pragma unroll
    for (int tt = 0; tt < 2; ++tt)
#pragma unroll
      for (int r = 0; r < 16; r += 4) {
        const float p0 = __builtin_amdgcn_exp2f((st[tt][r + 0] - mrun) * C);
        const float p1 = __builtin_amdgcn_exp2f((st[tt][r + 1] - mrun) * C);
        const float p2 = __builtin_amdgcn_exp2f((st[tt][r + 2] - mrun) * C);
        const float p3 = __builtin_amdgcn_exp2f((st[tt][r + 3] - mrun) * C);
        st[tt][r + 0] = p0; ra += p0;
        st[tt][r + 1] = p1; rb += p1;
        st[tt][r + 2] = p2; rc += p2;
        st[tt][r + 3] = p3; rd += p3;
      }
    float rs = (ra + rb) + (rc + rd);
    rs += __shfl_xor(rs, 32);
    lrun += rs;

    // P^T B-frags from S^T C/D via half-exchange (owner hf = j>>2):
    // pk[tt][g][p] packs keys m = 8g + 4*hf + 2p + {0,1} (consecutive dword)
    uint pk[2][4][2];
#pragma unroll
    for (int tt = 0; tt < 2; ++tt)
#pragma unroll
      for (int g = 0; g < 4; ++g)
#pragma unroll
        for (int p = 0; p < 2; ++p) {
          union { bf16 h2[2]; uint u; } cv;
          cv.h2[0] = (bf16)st[tt][4 * g + 2 * p];
          cv.h2[1] = (bf16)st[tt][4 * g + 2 * p + 1];
          pk[tt][g][p] = cv.u;
        }
    uint own_[2][2][2], rv[2][2][2];
#pragma unroll
    for (int tt = 0; tt < 2; ++tt)
#pragma unroll
      for (int gam = 0; gam < 2; ++gam)
#pragma unroll
        for (int p = 0; p < 2; ++p) {
          own_[tt][gam][p] = hf ? pk[tt][2 * gam + 1][p] : pk[tt][2 * gam][p];
          const uint snd = hf ? pk[tt][2 * gam][p] : pk[tt][2 * gam + 1][p];
          rv[tt][gam][p] = (uint)__shfl_xor((int)snd, 32);
        }
    // chunk c = tt*2+gam covers keys [c*16, c*16+16); dwords 0,1 from hf=0 owner
    __builtin_amdgcn_s_setprio(1);
#pragma unroll
    for (int c = 0; c < 4; ++c) {
      const int tt = c >> 1, gam = c & 1;
      union { uint u[4]; bf16x8 v; } pf;
      pf.u[0] = hf ? rv[tt][gam][0] : own_[tt][gam][0];
      pf.u[1] = hf ? rv[tt][gam][1] : own_[tt][gam][1];
      pf.u[2] = hf ? own_[tt][gam][0] : rv[tt][gam][0];
      pf.u[3] = hf ? own_[tt][gam][1] : rv[tt][gam][1];
      // O^T = V^T . P^T : A = V chunk (m = d'), B = P^T chunk (n = q)
#pragma unroll
      for (int n = 0; n < 2; ++n)
        o[n] = MFMA32(*(const bf16x8*)(Vb + (n * 4 + c) * 512 + lane * 8),
                      pf.v, o[n]);
    }
    __builtin_amdgcn_s_setprio(0);
  }

  if (seg < 0) {
    // full block: normalize, O^T C/D -> LDS transpose -> coalesced store.
    // lane holds O[q = qw+l31][d' = n*32 + (r&3)+8*(r>>2)+4*hf]
    const float inv = 1.f / lrun;
#pragma unroll
    for (int n = 0; n < 2; ++n)
#pragma unroll
      for (int r = 0; r < 16; ++r) {
        const int dl = n * 32 + (r & 3) + 8 * (r >> 2) + 4 * hf;
        Osh[(w * 32 + l31) * 66 + dl] = (bf16)(o[n][r] * inv);
      }
    __syncthreads();
#pragma unroll
    for (int i = 0; i < 4; ++i) {
      const int row = (t >> 3) + i * 32;
      const int col = (t & 7) * 8;
      const bf16x8 vv = *(const bf16x8*)&Osh[row * 66 + col];
      *(bf16x8*)&Ows[(q0 + row) * 2048 + h * 64 + col] = vv;
    }
  } else {
    // partial block: unnormalized fp32 O^T [d'][row] + per-row (m, l)
    const int idx = (h * 8 + (qt - 8)) * 2 + seg;
    float* Op = Opart + idx * 8192;
#pragma unroll
    for (int n = 0; n < 2; ++n)
#pragma unroll
      for (int r = 0; r < 16; ++r) {
        const int dl = n * 32 + (r & 3) + 8 * (r >> 2) + 4 * hf;
        Op[dl * 128 + w * 32 + l31] = o[n][r];
      }
    if (hf == 0) {
      ML[idx * 256 + w * 32 + l31] = mrun;
      ML[idx * 256 + 128 + w * 32 + l31] = lrun;
    }
  }
}

// ---------------------------------------------------------------------------
// Combine two KV-segment partials per (h, qt>=8): O = (O0*w0 + O1*w1)/denom.
// ---------------------------------------------------------------------------
__global__ __launch_bounds__(256) void combine_kernel(
    const float* __restrict__ Opart, const float* __restrict__ ML,
    bf16* __restrict__ Ows) {
  __shared__ bf16 Osh[128 * 66];
  const int b = blockIdx.x;
  const int h = b >> 3, qt = (b & 7) + 8;
  const int q0 = qt * 128;
  const int t = threadIdx.x;
  const int row = t & 127, dh = t >> 7;
  const int i0 = (h * 8 + (qt - 8)) * 2;
  const float C = 0.1803368801f;  // 0.125 * log2(e)
  const float m0 = ML[i0 * 256 + row], l0 = ML[i0 * 256 + 128 + row];
  const float m1 = ML[(i0 + 1) * 256 + row], l1 = ML[(i0 + 1) * 256 + 128 + row];
  const float m = fmaxf(m0, m1);
  const float w0 = __builtin_amdgcn_exp2f((m0 - m) * C);
  const float w1 = __builtin_amdgcn_exp2f((m1 - m) * C);
  const float inv = 1.f / (l0 * w0 + l1 * w1);
  const float* P0 = Opart + i0 * 8192;
  const float* P1 = Opart + (i0 + 1) * 8192;
#pragma unroll
  for (int j = 0; j < 32; ++j) {
    const int d = dh * 32 + j;
    const float v = (P0[d * 128 + row] * w0 + P1[d * 128 + row] * w1) * inv;
    Osh[row * 66 + d] = (bf16)v;
  }
  __syncthreads();
#pragma unroll
  for (int i = 0; i < 4; ++i) {
    const int r2 = (t >> 3) + i * 32;
    const int col = (t & 7) * 8;
    const bf16x8 vv = *(const bf16x8*)&Osh[r2 * 66 + col];
    *(bf16x8*)&Ows[(q0 + r2) * 2048 + h * 64 + col] = vv;
  }
}

// ---------------------------------------------------------------------------
extern "C" void kernel_launch(void* const* d_in, const int* in_sizes, int n_in,
                              void* d_out, int out_size, void* d_ws,
                              size_t ws_size, hipStream_t stream) {
  const float* x = (const float*)d_in[0];
  // d_in[1] = mask: causality recomputed in-kernel, unused.
  const float* wq = (const float*)d_in[2];
  const float* wk = (const float*)d_in[3];
  const float* wv = (const float*)d_in[4];
  const float* wo = (const float*)d_in[5];

  float* out = (float*)d_out;            // (2048, 2048) fp32
  float* kout = out + 4194304;           // (32, 2048, 64) fp32
  float* vout = out + 8388608;           // (32, 2048, 64) fp32

  bf16* ws = (bf16*)d_ws;
  bf16* xb = ws;                         // 2048 x 2048
  bf16* wqb = xb + 4194304;              // 2048 x 2048
  bf16* wkb = wqb + 4194304;             // 512 x 2048
  bf16* wvb = wkb + 1048576;             // 512 x 2048
  bf16* wob = wvb + 1048576;             // 2048 x 2048
  bf16* Qws = wob + 4194304;             // 2048 x 2048 (roped Q)
  bf16* Kws = Qws + 4194304;             // 2048 x 512 (now ML scratch only)
  bf16* Vws = Kws + 1048576;             // 2048 x 512 (unused)
  bf16* Vt = Vws + 1048576;              // 8 x 64 x 2048 (V^T per kv head)
  bf16* Ows = Vt + 1048576;              // 2048 x 2048 (attention out)
  bf16* Kh = Ows + 4194304;              // 8 x 2048 x 64 (roped K per kv head)
  // Scratch aliases (no new workspace): flash split-KV partials Opart = the
  // `out` region (rewritten by gemm_o); flash ML = Kws region (now otherwise
  // unused).
  float* Opart = out;
  float* MLf = (float*)Kws;              // 512 x 256 fp32 (m,l partials)

  convert_kernel<<<dim3(7168), dim3(256), 0, stream>>>(x, wq, wk, wv, wo, xb,
                                                       wqb, wkb, wvb, wob);
  gemm_qkv<<<dim3(24, 16), dim3(256), 0, stream>>>(xb, wqb, wkb, wvb, Qws, Kh,
                                                   Vt, kout, vout);
  flash_kernel<<<dim3(24, 32), dim3(256), 0, stream>>>(Qws, Kh, Vt, Ows, Opart,
                                                       MLf);
  combine_kernel<<<dim3(256), dim3(256), 0, stream>>>(Opart, MLf, Ows);
  gemm_o<<<dim3(16, 32), dim3(256), 0, stream>>>(Ows, wob, out);
}